// Round 3
// baseline (213.285 us; speedup 1.0000x reference)
//
#include <hip/hip_runtime.h>
#include <cstdint>
#include <cstddef>

#define D_MODEL 256
#define D_STATE 64
#define HEADDIM 64
#define D_INNER 512
#define NHEADS 8
#define D_XBC 640
#define NPROJ 1160
#define ZXW 1152   /* bf16 zxbc row width (z + xBC) */
#define BATCH 64
#define SEQ 250
#define ROWS (BATCH * SEQ) /* 16000 */
#define KIN 240
#define KPAD 256
#define NPAD 1280  /* padded to 10x128 col-panels for the 128x128-tile gemm1 */
#define TPAD 256  /* t padded to 256 in xcT */

typedef __bf16 bf16x8 __attribute__((ext_vector_type(8)));
typedef float f32x4 __attribute__((ext_vector_type(4)));

typedef __attribute__((address_space(1))) const void gv_t;
typedef __attribute__((address_space(3))) void lv_t;

__device__ __forceinline__ float readlane_f(float v, int lane) {
    return __uint_as_float(__builtin_amdgcn_readlane(__float_as_uint(v), lane));
}
__device__ __forceinline__ float silu_f(float x) { return x * (1.f / (1.f + __expf(-x))); }
__device__ __forceinline__ unsigned short bf16_rne(float f) {
    unsigned int u = __float_as_uint(f);
    u += 0x7fff + ((u >> 16) & 1);
    return (unsigned short)(u >> 16);
}
__device__ __forceinline__ float bf2f(unsigned short u) {
    return __uint_as_float(((unsigned int)u) << 16);
}
__device__ __forceinline__ unsigned int pack2(float a, float b) {
    return (unsigned int)bf16_rne(a) | ((unsigned int)bf16_rne(b) << 16);
}

// ---------------------------------------------------------------------------
// Kernel 0: cast_all — x -> a_bf [16000][256], W_in -> bt_bf [1280][256] (T),
// W_out -> wt_bf [256][512] (T). One launch for all three.
// ---------------------------------------------------------------------------
#define NA (ROWS * KPAD)
#define NB (NPAD * KPAD)
#define NW (D_MODEL * D_INNER)
__global__ __launch_bounds__(256) void cast_all_kernel(const float* __restrict__ x,
                                                       const float* __restrict__ Win,
                                                       const float* __restrict__ Wout,
                                                       unsigned short* __restrict__ a_bf,
                                                       unsigned short* __restrict__ bt_bf,
                                                       unsigned short* __restrict__ wt_bf) {
    int idx = blockIdx.x * 256 + threadIdx.x;
    if (idx < NA) {
        int row = idx >> 8, c = idx & 255;
        float v = (c < KIN) ? x[row * KIN + c] : 0.f;
        a_bf[idx] = bf16_rne(v);
    } else if (idx < NA + NB) {
        int r = idx - NA;
        int n = r >> 8, k = r & 255;
        float v = (n < NPROJ && k < KIN) ? Win[k * NPROJ + n] : 0.f;
        bt_bf[r] = bf16_rne(v);
    } else if (idx < NA + NB + NW) {
        int r = idx - NA - NB;
        int n = r & 255, k = r >> 8;
        wt_bf[n * D_INNER + k] = bf16_rne(Wout[k * D_MODEL + n]);
    }
}

// ---------------------------------------------------------------------------
// Kernel 1: gemm1 v2 — m97-structure: 128x128 tile, BK=32, linear LDS,
// global_load_lds width=16 staging. Grid 10 x 125. Writes bf16 zxbc
// (cols 0..1151) + fp32 dtraw (cols 1152..1159); cols >=1160 discarded.
// ---------------------------------------------------------------------------
__global__ __launch_bounds__(256) void gemm1_mfma(const unsigned short* __restrict__ A,
                                                  const unsigned short* __restrict__ Bt,
                                                  unsigned short* __restrict__ Czx,
                                                  float* __restrict__ dtraw) {
    __shared__ unsigned short As[128 * 32];
    __shared__ unsigned short Bs[128 * 32];
    const int tid = threadIdx.x;
    const int lane = tid & 63, wave = tid >> 6;
    const int wm = wave >> 1, wn = wave & 1;
    const int q = lane >> 4, l15 = lane & 15;
    const int rowBase = blockIdx.y * 128, colBase = blockIdx.x * 128;
    f32x4 acc[4][4] = {};

    const int sr = tid >> 2;          // staging row 0..63
    const int sc = (tid & 3) * 8;     // staging col (bf16) 0,8,16,24

    const unsigned short* gA = A + (size_t)(rowBase + sr) * KPAD + sc;
    const unsigned short* gB = Bt + (size_t)(colBase + sr) * KPAD + sc;
    unsigned short* lA = &As[sr * 32 + sc];   // == As + tid*8 (wave-uniform base + lane*16B)
    unsigned short* lB = &Bs[sr * 32 + sc];

    for (int k0 = 0; k0 < KPAD; k0 += 32) {
        __builtin_amdgcn_global_load_lds((gv_t*)(gA + k0), (lv_t*)lA, 16, 0, 0);
        __builtin_amdgcn_global_load_lds((gv_t*)(gA + 64 * KPAD + k0),
                                         (lv_t*)(lA + 64 * 32), 16, 0, 0);
        __builtin_amdgcn_global_load_lds((gv_t*)(gB + k0), (lv_t*)lB, 16, 0, 0);
        __builtin_amdgcn_global_load_lds((gv_t*)(gB + 64 * KPAD + k0),
                                         (lv_t*)(lB + 64 * 32), 16, 0, 0);
        __syncthreads();

        bf16x8 bfr[4];
#pragma unroll
        for (int nt = 0; nt < 4; nt++)
            bfr[nt] = *(const bf16x8*)&Bs[(wn * 64 + nt * 16 + l15) * 32 + q * 8];
#pragma unroll
        for (int mt = 0; mt < 4; mt++) {
            bf16x8 afr = *(const bf16x8*)&As[(wm * 64 + mt * 16 + l15) * 32 + q * 8];
#pragma unroll
            for (int nt = 0; nt < 4; nt++)
                acc[mt][nt] = __builtin_amdgcn_mfma_f32_16x16x32_bf16(afr, bfr[nt],
                                                                      acc[mt][nt], 0, 0, 0);
        }
        __syncthreads();
    }
#pragma unroll
    for (int mt = 0; mt < 4; mt++) {
        int grow0 = rowBase + wm * 64 + mt * 16 + q * 4;
#pragma unroll
        for (int nt = 0; nt < 4; nt++) {
            int gcol = colBase + wn * 64 + nt * 16 + l15;
            if (gcol < ZXW) {
#pragma unroll
                for (int reg = 0; reg < 4; reg++) {
                    unsigned int u = bf16_rne(acc[mt][nt][reg]);
                    unsigned int partner = (unsigned int)__shfl_xor((int)u, 1, 64);
                    if ((l15 & 1) == 0)
                        *(unsigned int*)&Czx[(size_t)(grow0 + reg) * ZXW + gcol] =
                            u | (partner << 16);
                }
            } else if (gcol < NPROJ) {
#pragma unroll
                for (int reg = 0; reg < 4; reg++)
                    dtraw[(size_t)(grow0 + reg) * NHEADS + (gcol - ZXW)] = acc[mt][nt][reg];
            }
        }
    }
}

// ---------------------------------------------------------------------------
// Kernel 2: conv v4 — tiled depthwise conv4 + SiLU from bf16 zxbc.
// Dead-store elimination: xc_bf only for B/C (cg>=8, ch 512..639, the only
// channels scan kernels read from xc); xcT_bf only for x/B (cg<=8, ch 0..575,
// the only channels read transposed). blockIdx.y==10: softplus(dt).
// ---------------------------------------------------------------------------
#define CT_IN_STR 68
#define CT_TR_STR 70
__global__ __launch_bounds__(256) void conv_kernel(const unsigned short* __restrict__ zxbc,
                                                   const float* __restrict__ dtraw,
                                                   const float* __restrict__ conv_w,
                                                   const float* __restrict__ conv_b,
                                                   const float* __restrict__ dt_bias,
                                                   unsigned short* __restrict__ xc_bf,
                                                   unsigned short* __restrict__ xcT_bf,
                                                   float* __restrict__ dtp) {
    const int b = blockIdx.x;
    const int t0 = blockIdx.z * 64;
    if (blockIdx.y == 10) {  // dt path: 64 t x 8 h
        for (int it = threadIdx.x; it < 512; it += 256) {
            int h = it & 7;
            int t = t0 + (it >> 3);
            if (t < SEQ) {
                float v = dtraw[(size_t)(b * SEQ + t) * NHEADS + h] + dt_bias[h];
                dtp[(size_t)(b * SEQ + t) * NHEADS + h] =
                    (v > 20.f) ? v : __logf(1.f + __expf(v));
            }
        }
        return;
    }
    __shared__ float In[67 * CT_IN_STR];
    __shared__ unsigned short OutT[64 * CT_TR_STR];
    const int cg = blockIdx.y;
    const int tid = threadIdx.x;
    const int lane = tid & 63;
    const int w = tid >> 6;
    const int ch = cg * 64 + lane;

    for (int r = w; r < 67; r += 4) {
        int t = t0 - 3 + r;
        float v = (t >= 0 && t < SEQ)
                      ? bf2f(zxbc[(size_t)(b * SEQ + t) * ZXW + D_INNER + ch])
                      : 0.f;
        In[r * CT_IN_STR + lane] = v;
    }
    __syncthreads();
    const float w0 = conv_w[ch * 4 + 0], w1 = conv_w[ch * 4 + 1];
    const float w2 = conv_w[ch * 4 + 2], w3 = conv_w[ch * 4 + 3];
    const float bias = conv_b[ch];
    unsigned short vals[16];
#pragma unroll
    for (int i = 0; i < 16; i++) {
        int tt = w * 16 + i;
        float acc = fmaf(w3, In[(tt + 3) * CT_IN_STR + lane],
                    fmaf(w2, In[(tt + 2) * CT_IN_STR + lane],
                    fmaf(w1, In[(tt + 1) * CT_IN_STR + lane],
                    fmaf(w0, In[tt * CT_IN_STR + lane], bias))));
        float sv = silu_f(acc);
        unsigned short bv = (t0 + tt < SEQ) ? bf16_rne(sv) : (unsigned short)0;
        vals[i] = bv;
        OutT[lane * CT_TR_STR + tt] = bv;
    }
    if (cg >= 8) {  // only B (cg==8) and C (cg==9) are read from xc_bf
#pragma unroll
        for (int i = 0; i < 16; i++) {
            int tt = w * 16 + i;
            if (t0 + tt < SEQ)
                xc_bf[(size_t)(b * SEQ + t0 + tt) * D_XBC + ch] = vals[i];
        }
    }
    if (cg <= 8) {  // only x (cg<8) and B (cg==8) are read from xcT_bf
        __syncthreads();
        unsigned short* dstbase = xcT_bf + ((size_t)b * D_XBC + cg * 64) * TPAD + t0;
#pragma unroll
        for (int i = 0; i < 16; i++) {
            int c2 = w * 16 + i;
            dstbase[(size_t)c2 * TPAD + lane] = OutT[c2 * CT_TR_STR + lane];
        }
    }
}

// ---------------------------------------------------------------------------
// Kernel 3a: scan_intra — one block per (b,h,chunk).
// ---------------------------------------------------------------------------
#define LSTR 72
__global__ __launch_bounds__(256) void scan_intra(const unsigned short* __restrict__ xc_bf,
                                                  const unsigned short* __restrict__ xcT_bf,
                                                  const float* __restrict__ dtp,
                                                  const float* __restrict__ A_log,
                                                  const float* __restrict__ Dvec,
                                                  unsigned short* __restrict__ yout_bf,
                                                  unsigned short* __restrict__ st_g) {
    __shared__ unsigned short C_l[64 * LSTR];   // C, then (post-S3) BwT
    __shared__ unsigned short BP_l[64 * LSTR];  // B, then (post-S3) P
    __shared__ unsigned short XT_l[64 * LSTR];  // x^T (plain)
    __shared__ float cs_s[64], dts_s[64], fws_s[64];

    const int blk = blockIdx.x;
    const int bh = blk >> 2, c = blk & 3;
    const int b = bh >> 3, h = bh & 7;
    const int tid = threadIdx.x;
    const int lane = tid & 63, w = tid >> 6;
    const int q = lane >> 4, l15 = lane & 15;
    const int t0 = c * 64;
    const float A = -__expf(A_log[h]);
    const float Dh = Dvec[h];

    const int r = tid >> 2, c0 = (tid & 3) * 16;

    {
        if (t0 + r < SEQ) {
            const unsigned short* rowp = xc_bf + (size_t)(b * SEQ + t0 + r) * D_XBC;
            *(uint4*)&C_l[r * LSTR + c0] = *(const uint4*)&rowp[D_INNER + D_STATE + c0];
            *(uint4*)&C_l[r * LSTR + c0 + 8] =
                *(const uint4*)&rowp[D_INNER + D_STATE + c0 + 8];
            *(uint4*)&BP_l[r * LSTR + c0] = *(const uint4*)&rowp[D_INNER + c0];
            *(uint4*)&BP_l[r * LSTR + c0 + 8] = *(const uint4*)&rowp[D_INNER + c0 + 8];
        } else {
            uint4 z = {0, 0, 0, 0};
            *(uint4*)&C_l[r * LSTR + c0] = z;
            *(uint4*)&C_l[r * LSTR + c0 + 8] = z;
            *(uint4*)&BP_l[r * LSTR + c0] = z;
            *(uint4*)&BP_l[r * LSTR + c0 + 8] = z;
        }
        const unsigned short* xrow =
            xcT_bf + ((size_t)b * D_XBC + h * HEADDIM + r) * TPAD + t0;
        *(uint4*)&XT_l[r * LSTR + c0] = *(const uint4*)&xrow[c0];
        *(uint4*)&XT_l[r * LSTR + c0 + 8] = *(const uint4*)&xrow[c0 + 8];
    }
    uint4 braw0, braw1;
    {
        const unsigned short* brow =
            xcT_bf + ((size_t)b * D_XBC + D_INNER + r) * TPAD + t0 + c0;
        braw0 = *(const uint4*)&brow[0];
        braw1 = *(const uint4*)&brow[8];
    }
    if (w == 0) {
        int t = lane;
        float dtv = (t0 + t < SEQ) ? dtp[(size_t)(b * SEQ + t0 + t) * NHEADS + h] : 0.f;
        float csv = dtv * A;
#pragma unroll
        for (int o = 1; o < 64; o <<= 1) {
            float u = __shfl_up(csv, o, 64);
            if (lane >= o) csv += u;
        }
        float tot = readlane_f(csv, 63);
        cs_s[t] = csv;
        dts_s[t] = dtv;
        fws_s[t] = dtv * __expf(tot - csv);
    }
    __syncthreads();  // S1

    f32x4 g[4] = {};
#pragma unroll
    for (int k0 = 0; k0 < 64; k0 += 32) {
        bf16x8 ca = *(const bf16x8*)&C_l[(w * 16 + l15) * LSTR + k0 + q * 8];
#pragma unroll
        for (int nt = 0; nt < 4; nt++) {
            bf16x8 bb = *(const bf16x8*)&BP_l[(nt * 16 + l15) * LSTR + k0 + q * 8];
            g[nt] = __builtin_amdgcn_mfma_f32_16x16x32_bf16(ca, bb, g[nt], 0, 0, 0);
        }
    }
    __syncthreads();  // S3

    {
        unsigned short tmp[16];
        const unsigned short* rp = (const unsigned short*)&braw0;
#pragma unroll
        for (int j = 0; j < 8; j++) tmp[j] = bf16_rne(bf2f(rp[j]) * fws_s[c0 + j]);
        rp = (const unsigned short*)&braw1;
#pragma unroll
        for (int j = 0; j < 8; j++) tmp[8 + j] = bf16_rne(bf2f(rp[j]) * fws_s[c0 + 8 + j]);
        *(uint4*)&C_l[r * LSTR + c0] = *(uint4*)&tmp[0];
        *(uint4*)&C_l[r * LSTR + c0 + 8] = *(uint4*)&tmp[8];
    }
#pragma unroll
    for (int nt = 0; nt < 4; nt++) {
#pragma unroll
        for (int rr = 0; rr < 4; rr++) {
            int t = w * 16 + q * 4 + rr;
            int s = nt * 16 + l15;
            float pv = 0.f;
            if (s <= t) {
                pv = g[nt][rr] * __expf(cs_s[t] - cs_s[s]) * dts_s[s];
                if (s == t) pv += Dh;
            }
            unsigned int u = bf16_rne(pv);
            unsigned int partner = (unsigned int)__shfl_xor((int)u, 1, 64);
            if ((l15 & 1) == 0)
                *(unsigned int*)&BP_l[t * LSTR + nt * 16 + l15] = u | (partner << 16);
        }
    }
    __syncthreads();  // S4

    f32x4 y[4] = {};
#pragma unroll
    for (int k0 = 0; k0 < 64; k0 += 32) {
        bf16x8 pa = *(const bf16x8*)&BP_l[(w * 16 + l15) * LSTR + k0 + q * 8];
#pragma unroll
        for (int nt = 0; nt < 4; nt++) {
            bf16x8 xb = *(const bf16x8*)&XT_l[(nt * 16 + l15) * LSTR + k0 + q * 8];
            y[nt] = __builtin_amdgcn_mfma_f32_16x16x32_bf16(pa, xb, y[nt], 0, 0, 0);
        }
    }
    if (c < 3) {
        f32x4 st[4] = {};
#pragma unroll
        for (int k0 = 0; k0 < 64; k0 += 32) {
            bf16x8 xa = *(const bf16x8*)&XT_l[(w * 16 + l15) * LSTR + k0 + q * 8];
#pragma unroll
            for (int nt = 0; nt < 4; nt++) {
                bf16x8 bwb = *(const bf16x8*)&C_l[(nt * 16 + l15) * LSTR + k0 + q * 8];
                st[nt] = __builtin_amdgcn_mfma_f32_16x16x32_bf16(xa, bwb, st[nt], 0, 0, 0);
            }
        }
        unsigned short* stc = st_g + ((size_t)(bh * 3 + c)) * 4096;
#pragma unroll
        for (int nt = 0; nt < 4; nt++)
#pragma unroll
            for (int rr = 0; rr < 4; rr++) {
                unsigned int u = bf16_rne(st[nt][rr]);
                unsigned int partner = (unsigned int)__shfl_xor((int)u, 1, 64);
                if ((l15 & 1) == 0)
                    *(unsigned int*)&stc[(w * 16 + q * 4 + rr) * 64 + nt * 16 + l15] =
                        u | (partner << 16);
            }
    }
#pragma unroll
    for (int nt = 0; nt < 4; nt++)
#pragma unroll
        for (int rr = 0; rr < 4; rr++) {
            int t = w * 16 + q * 4 + rr;
            if (t0 + t < SEQ) {
                int p = nt * 16 + l15;
                unsigned int u = bf16_rne(y[nt][rr]);
                unsigned int partner = (unsigned int)__shfl_xor((int)u, 1, 64);
                if ((l15 & 1) == 0)
                    *(unsigned int*)&yout_bf[(size_t)(b * SEQ + t0 + t) * D_INNER +
                                             h * HEADDIM + p] = u | (partner << 16);
            }
        }
}

// ---------------------------------------------------------------------------
// Kernel 3b: scan_inter — one block per (b,h,c), c in {1,2,3}.
// ---------------------------------------------------------------------------
__global__ __launch_bounds__(256) void scan_inter(const unsigned short* __restrict__ xc_bf,
                                                  const float* __restrict__ dtp,
                                                  const float* __restrict__ A_log,
                                                  unsigned short* __restrict__ yout_bf,
                                                  const unsigned short* __restrict__ st_g) {
    __shared__ unsigned short C_l[64 * LSTR];
    __shared__ unsigned short h_l[64 * LSTR];
    __shared__ float cs_s[64];
    __shared__ float csum[4];

    const int blk = blockIdx.x;
    const int bh = blk / 3, c = (blk - bh * 3) + 1;
    const int b = bh >> 3, h = bh & 7;
    const int tid = threadIdx.x;
    const int lane = tid & 63, w = tid >> 6;
    const int q = lane >> 4, l15 = lane & 15;
    const int t0 = c * 64;
    const float A = -__expf(A_log[h]);

    {
        int t = lane;
        int gt = w * 64 + t;
        float dtv = (gt < SEQ) ? dtp[(size_t)(b * SEQ + gt) * NHEADS + h] : 0.f;
        float csv = dtv * A;
#pragma unroll
        for (int o = 1; o < 64; o <<= 1) {
            float u = __shfl_up(csv, o, 64);
            if (lane >= o) csv += u;
        }
        if (w == c) cs_s[t] = csv;
        if (lane == 63) csum[w] = csv;
    }
    {
        int r = tid >> 2, c0 = (tid & 3) * 16;
        if (t0 + r < SEQ) {
            const unsigned short* rowp = xc_bf + (size_t)(b * SEQ + t0 + r) * D_XBC;
            *(uint4*)&C_l[r * LSTR + c0] = *(const uint4*)&rowp[D_INNER + D_STATE + c0];
            *(uint4*)&C_l[r * LSTR + c0 + 8] =
                *(const uint4*)&rowp[D_INNER + D_STATE + c0 + 8];
        } else {
            uint4 z = {0, 0, 0, 0};
            *(uint4*)&C_l[r * LSTR + c0] = z;
            *(uint4*)&C_l[r * LSTR + c0 + 8] = z;
        }
    }
    __syncthreads();

    {
        float wgt[3];
        for (int cp = 0; cp < c; cp++) {
            float s = 0.f;
            for (int j = cp + 1; j < c; j++) s += csum[j];
            wgt[cp] = __expf(s);
        }
        const unsigned short* stb = st_g + (size_t)bh * 3 * 4096;
        for (int i = tid; i < 4096; i += 256) {
            float acc = 0.f;
            for (int cp = 0; cp < c; cp++) acc += wgt[cp] * bf2f(stb[cp * 4096 + i]);
            h_l[(i >> 6) * LSTR + (i & 63)] = bf16_rne(acc);
        }
    }
    __syncthreads();

    f32x4 in[4] = {};
#pragma unroll
    for (int k0 = 0; k0 < 64; k0 += 32) {
        bf16x8 ca = *(const bf16x8*)&C_l[(w * 16 + l15) * LSTR + k0 + q * 8];
#pragma unroll
        for (int nt = 0; nt < 4; nt++) {
            bf16x8 hb = *(const bf16x8*)&h_l[(nt * 16 + l15) * LSTR + k0 + q * 8];
            in[nt] = __builtin_amdgcn_mfma_f32_16x16x32_bf16(ca, hb, in[nt], 0, 0, 0);
        }
    }
#pragma unroll
    for (int nt = 0; nt < 4; nt++)
#pragma unroll
        for (int r = 0; r < 4; r++) {
            int t = w * 16 + q * 4 + r;
            if (t0 + t < SEQ) {
                int p = nt * 16 + l15;
                size_t ai = (size_t)(b * SEQ + t0 + t) * D_INNER + h * HEADDIM + p;
                float alpha = __expf(cs_s[t]);
                float nv = bf2f(yout_bf[ai]) + alpha * in[nt][r];
                unsigned int u = bf16_rne(nv);
                unsigned int partner = (unsigned int)__shfl_xor((int)u, 1, 64);
                if ((l15 & 1) == 0)
                    *(unsigned int*)&yout_bf[ai] = u | (partner << 16);
            }
        }
}

// ---------------------------------------------------------------------------
// Kernel 5+6 fused: gemm2_fused v2 — out = selu( rms_r * ((y*silu(z)*norm_w) @ W^T) ).
// 64 rows/block (250 blocks): halves per-block B re-stage vs 32-row version,
// doubles MFMA per staging iteration. rms commutes through the GEMM.
// ---------------------------------------------------------------------------
#define SA 40
__global__ __launch_bounds__(256) void gemm2_fused(const unsigned short* __restrict__ yout_bf,
                                                   const unsigned short* __restrict__ zxbc,
                                                   const unsigned short* __restrict__ Bt,
                                                   const float* __restrict__ norm_w,
                                                   float* __restrict__ out) {
    __shared__ unsigned short As2[64 * SA];
    __shared__ unsigned short Bs2[256 * SA];
    __shared__ float rms_s[64];
    const int tid = threadIdx.x;
    const int lane = tid & 63;
    const int wn = tid >> 6;               // wave -> 64-col slice
    const int q = lane >> 4, l15 = lane & 15;
    const int rowBase = blockIdx.x * 64;
    f32x4 acc[4][4] = {};

    const int tr = tid >> 2;               // staging row 0..63
    const int tk = (tid & 3) * 8;          // staging k-offset 0,8,16,24

    const unsigned short* yrow = yout_bf + (size_t)(rowBase + tr) * D_INNER + tk;
    const unsigned short* zrow = zxbc + (size_t)(rowBase + tr) * ZXW + tk;
    float ssq = 0.f;

    for (int k0 = 0; k0 < D_INNER; k0 += 32) {
        // ---- A: u = y*silu(z)*norm_w (8 elems/thread), accumulate g^2 ----
        uint4 yp = *(const uint4*)&yrow[k0];
        uint4 zp = *(const uint4*)&zrow[k0];
        float4 nw0 = *(const float4*)&norm_w[k0 + tk];
        float4 nw1 = *(const float4*)&norm_w[k0 + tk + 4];
        const unsigned short* ys = (const unsigned short*)&yp;
        const unsigned short* zs = (const unsigned short*)&zp;
        float g[8];
#pragma unroll
        for (int i = 0; i < 8; i++) {
            g[i] = bf2f(ys[i]) * silu_f(bf2f(zs[i]));
            ssq = fmaf(g[i], g[i], ssq);
        }
        uint4 pk;
        pk.x = pack2(g[0] * nw0.x, g[1] * nw0.y);
        pk.y = pack2(g[2] * nw0.z, g[3] * nw0.w);
        pk.z = pack2(g[4] * nw1.x, g[5] * nw1.y);
        pk.w = pack2(g[6] * nw1.z, g[7] * nw1.w);
        *(uint4*)&As2[tr * SA + tk] = pk;
        // ---- B: col `tid`, 32 k-shorts ----
        const unsigned short* brow = Bt + (size_t)tid * D_INNER + k0;
        *(uint4*)&Bs2[tid * SA + 0] = *(const uint4*)&brow[0];
        *(uint4*)&Bs2[tid * SA + 8] = *(const uint4*)&brow[8];
        *(uint4*)&Bs2[tid * SA + 16] = *(const uint4*)&brow[16];
        *(uint4*)&Bs2[tid * SA + 24] = *(const uint4*)&brow[24];
        __syncthreads();

        bf16x8 bfr[4];
#pragma unroll
        for (int nt = 0; nt < 4; nt++)
            bfr[nt] = *(const bf16x8*)&Bs2[(wn * 64 + nt * 16 + l15) * SA + q * 8];
#pragma unroll
        for (int mt = 0; mt < 4; mt++) {
            bf16x8 afr = *(const bf16x8*)&As2[(mt * 16 + l15) * SA + q * 8];
#pragma unroll
            for (int nt = 0; nt < 4; nt++)
                acc[mt][nt] = __builtin_amdgcn_mfma_f32_16x16x32_bf16(afr, bfr[nt],
                                                                      acc[mt][nt], 0, 0, 0);
        }
        __syncthreads();
    }
    // per-row rms: reduce ssq over the 4 lanes (tid&3) that share row tr
    ssq += __shfl_xor(ssq, 1, 64);
    ssq += __shfl_xor(ssq, 2, 64);
    if ((tid & 3) == 0) rms_s[tr] = rsqrtf(ssq * (1.f / 512.f) + 1e-5f);
    __syncthreads();

    const float SC = 1.0507009873554805f, AL = 1.6732632423543772f;
#pragma unroll
    for (int mt = 0; mt < 4; mt++) {
        int lrow0 = mt * 16 + q * 4;
#pragma unroll
        for (int nt = 0; nt < 4; nt++) {
            int gcol = wn * 64 + nt * 16 + l15;
            if (gcol < 240) {
#pragma unroll
                for (int reg = 0; reg < 4; reg++) {
                    float v = acc[mt][nt][reg] * rms_s[lrow0 + reg];
                    v = (v > 0.f) ? SC * v : SC * AL * (__expf(v) - 1.f);
                    out[(size_t)(rowBase + lrow0 + reg) * 240 + gcol] = v;
                }
            }
        }
    }
}

// ---------------------------------------------------------------------------
extern "C" void kernel_launch(void* const* d_in, const int* in_sizes, int n_in,
                              void* d_out, int out_size, void* d_ws, size_t ws_size,
                              hipStream_t stream) {
    const float* x = (const float*)d_in[0];
    const float* W_in = (const float*)d_in[1];
    const float* conv_w = (const float*)d_in[2];
    const float* conv_b = (const float*)d_in[3];
    const float* A_log = (const float*)d_in[4];
    const float* dt_bias = (const float*)d_in[5];
    const float* Dv = (const float*)d_in[6];
    const float* norm_w = (const float*)d_in[7];
    const float* W_out = (const float*)d_in[8];
    float* out = (float*)d_out;

    unsigned short* us = (unsigned short*)d_ws;
    unsigned short* zxbc_bf = us;                              // 16000*1152
    unsigned short* xc_bf = zxbc_bf + (size_t)ROWS * ZXW;      // 16000*640
    unsigned short* xcT_bf = xc_bf + (size_t)ROWS * D_XBC;     // 64*640*256
    unsigned short* yout_bf = xcT_bf + (size_t)BATCH * D_XBC * TPAD;  // 16000*512
    unsigned short* st_g = yout_bf + (size_t)ROWS * D_INNER;   // 512*3*4096
    unsigned short* bt_bf = st_g + (size_t)512 * 3 * 4096;     // 1280*256
    unsigned short* wt_bf = bt_bf + (size_t)NPAD * KPAD;       // 256*512
    float* dtraw = (float*)(wt_bf + (size_t)D_MODEL * D_INNER);  // 16000*8
    float* dtp = dtraw + (size_t)ROWS * NHEADS;                // 16000*8
    unsigned short* a_bf = (unsigned short*)(dtp + (size_t)ROWS * NHEADS);  // 16000*256

    int cast_total = NA + NB + NW;
    cast_all_kernel<<<dim3((cast_total + 255) / 256), 256, 0, stream>>>(x, W_in, W_out,
                                                                        a_bf, bt_bf, wt_bf);

    gemm1_mfma<<<dim3(NPAD / 128, ROWS / 128), 256, 0, stream>>>(a_bf, bt_bf, zxbc_bf, dtraw);

    conv_kernel<<<dim3(BATCH, 11, 4), 256, 0, stream>>>(zxbc_bf, dtraw, conv_w, conv_b,
                                                        dt_bias, xc_bf, xcT_bf, dtp);

    scan_intra<<<dim3(BATCH * NHEADS * 4), 256, 0, stream>>>(xc_bf, xcT_bf, dtp, A_log, Dv,
                                                             yout_bf, st_g);

    scan_inter<<<dim3(BATCH * NHEADS * 3), 256, 0, stream>>>(xc_bf, dtp, A_log,
                                                             yout_bf, st_g);

    gemm2_fused<<<dim3(ROWS / 64), 256, 0, stream>>>(yout_bf, zxbc_bf, wt_bf, norm_w, out);
}

// Round 4
// 194.493 us; speedup vs baseline: 1.0966x; 1.0966x over previous
//
#include <hip/hip_runtime.h>
#include <cstdint>
#include <cstddef>

#define D_MODEL 256
#define D_STATE 64
#define HEADDIM 64
#define D_INNER 512
#define NHEADS 8
#define D_XBC 640
#define NPROJ 1160
#define ZXW 1152   /* bf16 zxbc row width (z + xBC) */
#define BATCH 64
#define SEQ 250
#define ROWS (BATCH * SEQ) /* 16000 */
#define KIN 240
#define KPAD 256
#define NPAD 1280  /* padded to 10x128 col-panels for the 128x128-tile gemm1 */
#define TPAD 256  /* t padded to 256 in xcT */

typedef __bf16 bf16x8 __attribute__((ext_vector_type(8)));
typedef float f32x4 __attribute__((ext_vector_type(4)));

typedef __attribute__((address_space(1))) const void gv_t;
typedef __attribute__((address_space(3))) void lv_t;

__device__ __forceinline__ float readlane_f(float v, int lane) {
    return __uint_as_float(__builtin_amdgcn_readlane(__float_as_uint(v), lane));
}
__device__ __forceinline__ float silu_f(float x) { return x * (1.f / (1.f + __expf(-x))); }
__device__ __forceinline__ unsigned short bf16_rne(float f) {
    unsigned int u = __float_as_uint(f);
    u += 0x7fff + ((u >> 16) & 1);
    return (unsigned short)(u >> 16);
}
__device__ __forceinline__ float bf2f(unsigned short u) {
    return __uint_as_float(((unsigned int)u) << 16);
}
__device__ __forceinline__ unsigned int pack2(float a, float b) {
    return (unsigned int)bf16_rne(a) | ((unsigned int)bf16_rne(b) << 16);
}

// ---------------------------------------------------------------------------
// Kernel 0: cast_all — x -> a_bf [16000][256], W_in -> bt_bf [1280][256] (T),
// W_out -> wt_bf [256][512] (T). One launch for all three.
// ---------------------------------------------------------------------------
#define NA (ROWS * KPAD)
#define NB (NPAD * KPAD)
#define NW (D_MODEL * D_INNER)
__global__ __launch_bounds__(256) void cast_all_kernel(const float* __restrict__ x,
                                                       const float* __restrict__ Win,
                                                       const float* __restrict__ Wout,
                                                       unsigned short* __restrict__ a_bf,
                                                       unsigned short* __restrict__ bt_bf,
                                                       unsigned short* __restrict__ wt_bf) {
    int idx = blockIdx.x * 256 + threadIdx.x;
    if (idx < NA) {
        int row = idx >> 8, c = idx & 255;
        float v = (c < KIN) ? x[row * KIN + c] : 0.f;
        a_bf[idx] = bf16_rne(v);
    } else if (idx < NA + NB) {
        int r = idx - NA;
        int n = r >> 8, k = r & 255;
        float v = (n < NPROJ && k < KIN) ? Win[k * NPROJ + n] : 0.f;
        bt_bf[r] = bf16_rne(v);
    } else if (idx < NA + NB + NW) {
        int r = idx - NA - NB;
        int n = r & 255, k = r >> 8;
        wt_bf[n * D_INNER + k] = bf16_rne(Wout[k * D_MODEL + n]);
    }
}

// ---------------------------------------------------------------------------
// Kernel 1: gemm1 v2 — m97-structure: 128x128 tile, BK=32, linear LDS,
// global_load_lds width=16 staging. Grid 10 x 125. Writes bf16 zxbc
// (cols 0..1151) + fp32 dtraw (cols 1152..1159); cols >=1160 discarded.
// ---------------------------------------------------------------------------
__global__ __launch_bounds__(256) void gemm1_mfma(const unsigned short* __restrict__ A,
                                                  const unsigned short* __restrict__ Bt,
                                                  unsigned short* __restrict__ Czx,
                                                  float* __restrict__ dtraw) {
    __shared__ unsigned short As[128 * 32];
    __shared__ unsigned short Bs[128 * 32];
    const int tid = threadIdx.x;
    const int lane = tid & 63, wave = tid >> 6;
    const int wm = wave >> 1, wn = wave & 1;
    const int q = lane >> 4, l15 = lane & 15;
    const int rowBase = blockIdx.y * 128, colBase = blockIdx.x * 128;
    f32x4 acc[4][4] = {};

    const int sr = tid >> 2;          // staging row 0..63
    const int sc = (tid & 3) * 8;     // staging col (bf16) 0,8,16,24

    const unsigned short* gA = A + (size_t)(rowBase + sr) * KPAD + sc;
    const unsigned short* gB = Bt + (size_t)(colBase + sr) * KPAD + sc;
    unsigned short* lA = &As[sr * 32 + sc];   // == As + tid*8 (wave-uniform base + lane*16B)
    unsigned short* lB = &Bs[sr * 32 + sc];

    for (int k0 = 0; k0 < KPAD; k0 += 32) {
        __builtin_amdgcn_global_load_lds((gv_t*)(gA + k0), (lv_t*)lA, 16, 0, 0);
        __builtin_amdgcn_global_load_lds((gv_t*)(gA + 64 * KPAD + k0),
                                         (lv_t*)(lA + 64 * 32), 16, 0, 0);
        __builtin_amdgcn_global_load_lds((gv_t*)(gB + k0), (lv_t*)lB, 16, 0, 0);
        __builtin_amdgcn_global_load_lds((gv_t*)(gB + 64 * KPAD + k0),
                                         (lv_t*)(lB + 64 * 32), 16, 0, 0);
        __syncthreads();

        bf16x8 bfr[4];
#pragma unroll
        for (int nt = 0; nt < 4; nt++)
            bfr[nt] = *(const bf16x8*)&Bs[(wn * 64 + nt * 16 + l15) * 32 + q * 8];
#pragma unroll
        for (int mt = 0; mt < 4; mt++) {
            bf16x8 afr = *(const bf16x8*)&As[(wm * 64 + mt * 16 + l15) * 32 + q * 8];
#pragma unroll
            for (int nt = 0; nt < 4; nt++)
                acc[mt][nt] = __builtin_amdgcn_mfma_f32_16x16x32_bf16(afr, bfr[nt],
                                                                      acc[mt][nt], 0, 0, 0);
        }
        __syncthreads();
    }
#pragma unroll
    for (int mt = 0; mt < 4; mt++) {
        int grow0 = rowBase + wm * 64 + mt * 16 + q * 4;
#pragma unroll
        for (int nt = 0; nt < 4; nt++) {
            int gcol = colBase + wn * 64 + nt * 16 + l15;
            if (gcol < ZXW) {
#pragma unroll
                for (int reg = 0; reg < 4; reg++) {
                    unsigned int u = bf16_rne(acc[mt][nt][reg]);
                    unsigned int partner = (unsigned int)__shfl_xor((int)u, 1, 64);
                    if ((l15 & 1) == 0)
                        *(unsigned int*)&Czx[(size_t)(grow0 + reg) * ZXW + gcol] =
                            u | (partner << 16);
                }
            } else if (gcol < NPROJ) {
#pragma unroll
                for (int reg = 0; reg < 4; reg++)
                    dtraw[(size_t)(grow0 + reg) * NHEADS + (gcol - ZXW)] = acc[mt][nt][reg];
            }
        }
    }
}

// ---------------------------------------------------------------------------
// Kernel 2: conv v4 — tiled depthwise conv4 + SiLU from bf16 zxbc.
// Dead-store elimination: xc_bf only for B/C (cg>=8); xcT_bf only for x/B
// (cg<=8). blockIdx.y==10: softplus(dt).
// ---------------------------------------------------------------------------
#define CT_IN_STR 68
#define CT_TR_STR 70
__global__ __launch_bounds__(256) void conv_kernel(const unsigned short* __restrict__ zxbc,
                                                   const float* __restrict__ dtraw,
                                                   const float* __restrict__ conv_w,
                                                   const float* __restrict__ conv_b,
                                                   const float* __restrict__ dt_bias,
                                                   unsigned short* __restrict__ xc_bf,
                                                   unsigned short* __restrict__ xcT_bf,
                                                   float* __restrict__ dtp) {
    const int b = blockIdx.x;
    const int t0 = blockIdx.z * 64;
    if (blockIdx.y == 10) {  // dt path: 64 t x 8 h
        for (int it = threadIdx.x; it < 512; it += 256) {
            int h = it & 7;
            int t = t0 + (it >> 3);
            if (t < SEQ) {
                float v = dtraw[(size_t)(b * SEQ + t) * NHEADS + h] + dt_bias[h];
                dtp[(size_t)(b * SEQ + t) * NHEADS + h] =
                    (v > 20.f) ? v : __logf(1.f + __expf(v));
            }
        }
        return;
    }
    __shared__ float In[67 * CT_IN_STR];
    __shared__ unsigned short OutT[64 * CT_TR_STR];
    const int cg = blockIdx.y;
    const int tid = threadIdx.x;
    const int lane = tid & 63;
    const int w = tid >> 6;
    const int ch = cg * 64 + lane;

    for (int r = w; r < 67; r += 4) {
        int t = t0 - 3 + r;
        float v = (t >= 0 && t < SEQ)
                      ? bf2f(zxbc[(size_t)(b * SEQ + t) * ZXW + D_INNER + ch])
                      : 0.f;
        In[r * CT_IN_STR + lane] = v;
    }
    __syncthreads();
    const float w0 = conv_w[ch * 4 + 0], w1 = conv_w[ch * 4 + 1];
    const float w2 = conv_w[ch * 4 + 2], w3 = conv_w[ch * 4 + 3];
    const float bias = conv_b[ch];
    unsigned short vals[16];
#pragma unroll
    for (int i = 0; i < 16; i++) {
        int tt = w * 16 + i;
        float acc = fmaf(w3, In[(tt + 3) * CT_IN_STR + lane],
                    fmaf(w2, In[(tt + 2) * CT_IN_STR + lane],
                    fmaf(w1, In[(tt + 1) * CT_IN_STR + lane],
                    fmaf(w0, In[tt * CT_IN_STR + lane], bias))));
        float sv = silu_f(acc);
        unsigned short bv = (t0 + tt < SEQ) ? bf16_rne(sv) : (unsigned short)0;
        vals[i] = bv;
        OutT[lane * CT_TR_STR + tt] = bv;
    }
    if (cg >= 8) {  // only B (cg==8) and C (cg==9) are read from xc_bf
#pragma unroll
        for (int i = 0; i < 16; i++) {
            int tt = w * 16 + i;
            if (t0 + tt < SEQ)
                xc_bf[(size_t)(b * SEQ + t0 + tt) * D_XBC + ch] = vals[i];
        }
    }
    if (cg <= 8) {  // only x (cg<8) and B (cg==8) are read from xcT_bf
        __syncthreads();
        unsigned short* dstbase = xcT_bf + ((size_t)b * D_XBC + cg * 64) * TPAD + t0;
#pragma unroll
        for (int i = 0; i < 16; i++) {
            int c2 = w * 16 + i;
            dstbase[(size_t)c2 * TPAD + lane] = OutT[c2 * CT_TR_STR + lane];
        }
    }
}

// ---------------------------------------------------------------------------
// Kernel 3: scan_fused — one block per (b,h); 4 chunks sequential, inter-chunk
// state h carried in f32 registers (st fragment layout) + bf16 LDS mirror.
// Eliminates st_g round-trip, yout RMW, and scan_inter's C re-read.
//   h_c = st_c + exp(csum_c) * h_{c-1};  y_t = y_intra + exp(cs_t) * (C_t . h_{c-1})
// ---------------------------------------------------------------------------
#define LSTR 72
__global__ __launch_bounds__(256) void scan_fused(const unsigned short* __restrict__ xc_bf,
                                                  const unsigned short* __restrict__ xcT_bf,
                                                  const float* __restrict__ dtp,
                                                  const float* __restrict__ A_log,
                                                  const float* __restrict__ Dvec,
                                                  unsigned short* __restrict__ yout_bf) {
    __shared__ unsigned short C_l[64 * LSTR];   // C, then (post-S3) BwT
    __shared__ unsigned short BP_l[64 * LSTR];  // B, then (post-S3) P
    __shared__ unsigned short XT_l[64 * LSTR];  // x^T
    __shared__ unsigned short H_l[64 * LSTR];   // h_{c-1} as bf16, [p][n]
    __shared__ float cs_s[64], dts_s[64], fws_s[64];
    __shared__ float tot_s;

    const int bh = blockIdx.x;
    const int b = bh >> 3, h = bh & 7;
    const int tid = threadIdx.x;
    const int lane = tid & 63, w = tid >> 6;
    const int q = lane >> 4, l15 = lane & 15;
    const float A = -__expf(A_log[h]);
    const float Dh = Dvec[h];
    const int r = tid >> 2, c0 = (tid & 3) * 16;

    f32x4 h_acc[4] = {};  // rows p = w*16+q*4+rr, cols n = nt*16+l15

    for (int c = 0; c < 4; ++c) {
        const int t0 = c * 64;
        if (c > 0) __syncthreads();  // S0: prev-chunk LDS reads done before overwrite

        if (t0 + r < SEQ) {
            const unsigned short* rowp = xc_bf + (size_t)(b * SEQ + t0 + r) * D_XBC;
            *(uint4*)&C_l[r * LSTR + c0] = *(const uint4*)&rowp[D_INNER + D_STATE + c0];
            *(uint4*)&C_l[r * LSTR + c0 + 8] =
                *(const uint4*)&rowp[D_INNER + D_STATE + c0 + 8];
            *(uint4*)&BP_l[r * LSTR + c0] = *(const uint4*)&rowp[D_INNER + c0];
            *(uint4*)&BP_l[r * LSTR + c0 + 8] = *(const uint4*)&rowp[D_INNER + c0 + 8];
        } else {
            uint4 z = {0, 0, 0, 0};
            *(uint4*)&C_l[r * LSTR + c0] = z;
            *(uint4*)&C_l[r * LSTR + c0 + 8] = z;
            *(uint4*)&BP_l[r * LSTR + c0] = z;
            *(uint4*)&BP_l[r * LSTR + c0 + 8] = z;
        }
        {
            const unsigned short* xrow =
                xcT_bf + ((size_t)b * D_XBC + h * HEADDIM + r) * TPAD + t0;
            *(uint4*)&XT_l[r * LSTR + c0] = *(const uint4*)&xrow[c0];
            *(uint4*)&XT_l[r * LSTR + c0 + 8] = *(const uint4*)&xrow[c0 + 8];
        }
        uint4 braw0, braw1;
        {
            const unsigned short* brow =
                xcT_bf + ((size_t)b * D_XBC + D_INNER + r) * TPAD + t0 + c0;
            braw0 = *(const uint4*)&brow[0];
            braw1 = *(const uint4*)&brow[8];
        }
        if (w == 0) {
            int t = lane;
            float dtv = (t0 + t < SEQ) ? dtp[(size_t)(b * SEQ + t0 + t) * NHEADS + h] : 0.f;
            float csv = dtv * A;
#pragma unroll
            for (int o = 1; o < 64; o <<= 1) {
                float u = __shfl_up(csv, o, 64);
                if (lane >= o) csv += u;
            }
            float tot = readlane_f(csv, 63);
            cs_s[t] = csv;
            dts_s[t] = dtv;
            fws_s[t] = dtv * __expf(tot - csv);
            if (lane == 0) tot_s = tot;
        }
        __syncthreads();  // S1

        // G = C . B^T  and  y_inter = C . h_{c-1}^T
        f32x4 g[4] = {};
        f32x4 yi[4] = {};
#pragma unroll
        for (int k0 = 0; k0 < 64; k0 += 32) {
            bf16x8 ca = *(const bf16x8*)&C_l[(w * 16 + l15) * LSTR + k0 + q * 8];
#pragma unroll
            for (int nt = 0; nt < 4; nt++) {
                bf16x8 bb = *(const bf16x8*)&BP_l[(nt * 16 + l15) * LSTR + k0 + q * 8];
                g[nt] = __builtin_amdgcn_mfma_f32_16x16x32_bf16(ca, bb, g[nt], 0, 0, 0);
            }
            if (c > 0) {
#pragma unroll
                for (int nt = 0; nt < 4; nt++) {
                    bf16x8 hb = *(const bf16x8*)&H_l[(nt * 16 + l15) * LSTR + k0 + q * 8];
                    yi[nt] = __builtin_amdgcn_mfma_f32_16x16x32_bf16(ca, hb, yi[nt], 0, 0, 0);
                }
            }
        }
        __syncthreads();  // S3

        {   // C_l <- Bw (B^T row-scaled by fws)
            unsigned short tmp[16];
            const unsigned short* rp = (const unsigned short*)&braw0;
#pragma unroll
            for (int j = 0; j < 8; j++) tmp[j] = bf16_rne(bf2f(rp[j]) * fws_s[c0 + j]);
            rp = (const unsigned short*)&braw1;
#pragma unroll
            for (int j = 0; j < 8; j++) tmp[8 + j] = bf16_rne(bf2f(rp[j]) * fws_s[c0 + 8 + j]);
            *(uint4*)&C_l[r * LSTR + c0] = *(uint4*)&tmp[0];
            *(uint4*)&C_l[r * LSTR + c0 + 8] = *(uint4*)&tmp[8];
        }
#pragma unroll
        for (int nt = 0; nt < 4; nt++) {   // BP_l <- P
#pragma unroll
            for (int rr = 0; rr < 4; rr++) {
                int t = w * 16 + q * 4 + rr;
                int s = nt * 16 + l15;
                float pv = 0.f;
                if (s <= t) {
                    pv = g[nt][rr] * __expf(cs_s[t] - cs_s[s]) * dts_s[s];
                    if (s == t) pv += Dh;
                }
                unsigned int u = bf16_rne(pv);
                unsigned int partner = (unsigned int)__shfl_xor((int)u, 1, 64);
                if ((l15 & 1) == 0)
                    *(unsigned int*)&BP_l[t * LSTR + nt * 16 + l15] = u | (partner << 16);
            }
        }
        __syncthreads();  // S4

        // y_intra = P . x^T
        f32x4 y[4] = {};
#pragma unroll
        for (int k0 = 0; k0 < 64; k0 += 32) {
            bf16x8 pa = *(const bf16x8*)&BP_l[(w * 16 + l15) * LSTR + k0 + q * 8];
#pragma unroll
            for (int nt = 0; nt < 4; nt++) {
                bf16x8 xb = *(const bf16x8*)&XT_l[(nt * 16 + l15) * LSTR + k0 + q * 8];
                y[nt] = __builtin_amdgcn_mfma_f32_16x16x32_bf16(pa, xb, y[nt], 0, 0, 0);
            }
        }
        if (c < 3) {
            // st = x~ . Bw^T ; h update; H_l <- bf16(h)
            f32x4 st[4] = {};
#pragma unroll
            for (int k0 = 0; k0 < 64; k0 += 32) {
                bf16x8 xa = *(const bf16x8*)&XT_l[(w * 16 + l15) * LSTR + k0 + q * 8];
#pragma unroll
                for (int nt = 0; nt < 4; nt++) {
                    bf16x8 bwb = *(const bf16x8*)&C_l[(nt * 16 + l15) * LSTR + k0 + q * 8];
                    st[nt] = __builtin_amdgcn_mfma_f32_16x16x32_bf16(xa, bwb, st[nt], 0, 0, 0);
                }
            }
            const float decay = __expf(tot_s);
#pragma unroll
            for (int nt = 0; nt < 4; nt++) {
                h_acc[nt] = st[nt] + decay * h_acc[nt];
#pragma unroll
                for (int rr = 0; rr < 4; rr++) {
                    unsigned int u = bf16_rne(h_acc[nt][rr]);
                    unsigned int partner = (unsigned int)__shfl_xor((int)u, 1, 64);
                    if ((l15 & 1) == 0)
                        *(unsigned int*)&H_l[(w * 16 + q * 4 + rr) * LSTR + nt * 16 + l15] =
                            u | (partner << 16);
                }
            }
        }
        // yout = y_intra + exp(cs_t) * y_inter  (single write, no RMW)
#pragma unroll
        for (int nt = 0; nt < 4; nt++)
#pragma unroll
            for (int rr = 0; rr < 4; rr++) {
                int t = w * 16 + q * 4 + rr;
                if (t0 + t < SEQ) {
                    int p = nt * 16 + l15;
                    float yv = y[nt][rr];
                    if (c > 0) yv += __expf(cs_s[t]) * yi[nt][rr];
                    unsigned int u = bf16_rne(yv);
                    unsigned int partner = (unsigned int)__shfl_xor((int)u, 1, 64);
                    if ((l15 & 1) == 0)
                        *(unsigned int*)&yout_bf[(size_t)(b * SEQ + t0 + t) * D_INNER +
                                                 h * HEADDIM + p] = u | (partner << 16);
                }
            }
    }
}

// ---------------------------------------------------------------------------
// Kernel 5+6 fused: gemm2_fused — out = selu( rms_r * ((y*silu(z)*norm_w) @ W^T) ).
// R2-proven 32-row/500-block version (grid must stay >= 2x CU count).
// ---------------------------------------------------------------------------
#define SA 40
__global__ __launch_bounds__(256) void gemm2_fused(const unsigned short* __restrict__ yout_bf,
                                                   const unsigned short* __restrict__ zxbc,
                                                   const unsigned short* __restrict__ Bt,
                                                   const float* __restrict__ norm_w,
                                                   float* __restrict__ out) {
    __shared__ unsigned short As2[32 * SA];
    __shared__ unsigned short Bs2[256 * SA];
    __shared__ float rms_s[32];
    const int tid = threadIdx.x;
    const int lane = tid & 63;
    const int wn = tid >> 6;               // wave -> 64-col slice
    const int q = lane >> 4, l15 = lane & 15;
    const int rowBase = blockIdx.x * 32;
    f32x4 acc[2][4] = {};

    const int tr = tid >> 3;               // staging row 0..31
    const int tk = (tid & 7) * 4;          // staging k-offset 0..28

    const unsigned short* yrow = yout_bf + (size_t)(rowBase + tr) * D_INNER + tk;
    const unsigned short* zrow = zxbc + (size_t)(rowBase + tr) * ZXW + tk;
    float ssq = 0.f;

    for (int k0 = 0; k0 < D_INNER; k0 += 32) {
        // ---- A: u = y*silu(z)*norm_w, accumulate g^2 ----
        uint2 yp = *(const uint2*)&yrow[k0];
        uint2 zp = *(const uint2*)&zrow[k0];
        float4 nw = *(const float4*)&norm_w[k0 + tk];
        const unsigned short* ys = (const unsigned short*)&yp;
        const unsigned short* zs = (const unsigned short*)&zp;
        float g0 = bf2f(ys[0]) * silu_f(bf2f(zs[0]));
        float g1 = bf2f(ys[1]) * silu_f(bf2f(zs[1]));
        float g2 = bf2f(ys[2]) * silu_f(bf2f(zs[2]));
        float g3 = bf2f(ys[3]) * silu_f(bf2f(zs[3]));
        ssq = fmaf(g0, g0, ssq);
        ssq = fmaf(g1, g1, ssq);
        ssq = fmaf(g2, g2, ssq);
        ssq = fmaf(g3, g3, ssq);
        uint2 pk;
        pk.x = pack2(g0 * nw.x, g1 * nw.y);
        pk.y = pack2(g2 * nw.z, g3 * nw.w);
        *(uint2*)&As2[tr * SA + tk] = pk;
        // ---- B: col `tid`, 32 k-shorts ----
        const unsigned short* brow = Bt + (size_t)tid * D_INNER + k0;
        *(uint4*)&Bs2[tid * SA + 0] = *(const uint4*)&brow[0];
        *(uint4*)&Bs2[tid * SA + 8] = *(const uint4*)&brow[8];
        *(uint4*)&Bs2[tid * SA + 16] = *(const uint4*)&brow[16];
        *(uint4*)&Bs2[tid * SA + 24] = *(const uint4*)&brow[24];
        __syncthreads();

        bf16x8 bfr[4];
#pragma unroll
        for (int nt = 0; nt < 4; nt++)
            bfr[nt] = *(const bf16x8*)&Bs2[(wn * 64 + nt * 16 + l15) * SA + q * 8];
#pragma unroll
        for (int mt = 0; mt < 2; mt++) {
            bf16x8 afr = *(const bf16x8*)&As2[(mt * 16 + l15) * SA + q * 8];
#pragma unroll
            for (int nt = 0; nt < 4; nt++)
                acc[mt][nt] = __builtin_amdgcn_mfma_f32_16x16x32_bf16(afr, bfr[nt],
                                                                      acc[mt][nt], 0, 0, 0);
        }
        __syncthreads();
    }
    // per-row rms: reduce ssq over the 8 lanes (tid&7) that share row tr
    ssq += __shfl_xor(ssq, 1, 64);
    ssq += __shfl_xor(ssq, 2, 64);
    ssq += __shfl_xor(ssq, 4, 64);
    if ((tid & 7) == 0) rms_s[tr] = rsqrtf(ssq * (1.f / 512.f) + 1e-5f);
    __syncthreads();

    const float SC = 1.0507009873554805f, AL = 1.6732632423543772f;
#pragma unroll
    for (int mt = 0; mt < 2; mt++) {
        int lrow0 = mt * 16 + q * 4;
#pragma unroll
        for (int nt = 0; nt < 4; nt++) {
            int gcol = wn * 64 + nt * 16 + l15;
            if (gcol < 240) {
#pragma unroll
                for (int reg = 0; reg < 4; reg++) {
                    float v = acc[mt][nt][reg] * rms_s[lrow0 + reg];
                    v = (v > 0.f) ? SC * v : SC * AL * (__expf(v) - 1.f);
                    out[(size_t)(rowBase + lrow0 + reg) * 240 + gcol] = v;
                }
            }
        }
    }
}

// ---------------------------------------------------------------------------
extern "C" void kernel_launch(void* const* d_in, const int* in_sizes, int n_in,
                              void* d_out, int out_size, void* d_ws, size_t ws_size,
                              hipStream_t stream) {
    const float* x = (const float*)d_in[0];
    const float* W_in = (const float*)d_in[1];
    const float* conv_w = (const float*)d_in[2];
    const float* conv_b = (const float*)d_in[3];
    const float* A_log = (const float*)d_in[4];
    const float* dt_bias = (const float*)d_in[5];
    const float* Dv = (const float*)d_in[6];
    const float* norm_w = (const float*)d_in[7];
    const float* W_out = (const float*)d_in[8];
    float* out = (float*)d_out;

    unsigned short* us = (unsigned short*)d_ws;
    unsigned short* zxbc_bf = us;                              // 16000*1152
    unsigned short* xc_bf = zxbc_bf + (size_t)ROWS * ZXW;      // 16000*640
    unsigned short* xcT_bf = xc_bf + (size_t)ROWS * D_XBC;     // 64*640*256
    unsigned short* yout_bf = xcT_bf + (size_t)BATCH * D_XBC * TPAD;  // 16000*512
    unsigned short* st_g = yout_bf + (size_t)ROWS * D_INNER;   // (unused now)
    unsigned short* bt_bf = st_g + (size_t)512 * 3 * 4096;     // 1280*256
    unsigned short* wt_bf = bt_bf + (size_t)NPAD * KPAD;       // 256*512
    float* dtraw = (float*)(wt_bf + (size_t)D_MODEL * D_INNER);  // 16000*8
    float* dtp = dtraw + (size_t)ROWS * NHEADS;                // 16000*8
    unsigned short* a_bf = (unsigned short*)(dtp + (size_t)ROWS * NHEADS);  // 16000*256

    int cast_total = NA + NB + NW;
    cast_all_kernel<<<dim3((cast_total + 255) / 256), 256, 0, stream>>>(x, W_in, W_out,
                                                                        a_bf, bt_bf, wt_bf);

    gemm1_mfma<<<dim3(NPAD / 128, ROWS / 128), 256, 0, stream>>>(a_bf, bt_bf, zxbc_bf, dtraw);

    conv_kernel<<<dim3(BATCH, 11, 4), 256, 0, stream>>>(zxbc_bf, dtraw, conv_w, conv_b,
                                                        dt_bias, xc_bf, xcT_bf, dtp);

    scan_fused<<<dim3(BATCH * NHEADS), 256, 0, stream>>>(xc_bf, xcT_bf, dtp, A_log, Dv,
                                                         yout_bf);

    gemm2_fused<<<dim3(ROWS / 32), 256, 0, stream>>>(yout_bf, zxbc_bf, wt_bf, norm_w, out);
}